// Round 13
// baseline (200.397 us; speedup 1.0000x reference)
//
#include <hip/hip_runtime.h>
#include <hip/hip_bf16.h>

typedef __hip_bfloat16 bf16;
typedef _Float16 f16;
typedef __attribute__((ext_vector_type(8))) __bf16 bf16x8;
typedef __attribute__((ext_vector_type(8))) _Float16 f16x8;
typedef __attribute__((ext_vector_type(4))) _Float16 f16x4;
typedef __attribute__((ext_vector_type(4))) float floatx4;
typedef __attribute__((ext_vector_type(16))) float floatx16;

#define T_SEQ 2048
#define EMB   1024
#define LAMBDA_INIT 0.35550906759096926f

// round-to-nearest-even fp32 -> bf16
__device__ __forceinline__ bf16 f2bf(float f) {
  unsigned u;
  __builtin_memcpy(&u, &f, 4);
  u += 0x7FFF + ((u >> 16) & 1);
  unsigned short h = (unsigned short)(u >> 16);
  bf16 r;
  __builtin_memcpy(&r, &h, 2);
  return r;
}

__device__ __forceinline__ void gl_lds16(const void* g, void* l) {
  __builtin_amdgcn_global_load_lds((const __attribute__((address_space(1))) void*)g,
                                   (__attribute__((address_space(3))) void*)l, 16, 0, 0);
}

__device__ __forceinline__ floatx4 mfma_h(f16x8 a, f16x8 b, floatx4 c) {
  return __builtin_amdgcn_mfma_f32_16x16x32_f16(a, b, c, 0, 0, 0);
}
__device__ __forceinline__ floatx16 mfma32_h(f16x8 a, f16x8 b, floatx16 c) {
  return __builtin_amdgcn_mfma_f32_32x32x16_f16(a, b, c, 0, 0, 0);
}
__device__ __forceinline__ floatx16 mfma32_bf(bf16x8 a, bf16x8 b, floatx16 c) {
  return __builtin_amdgcn_mfma_f32_32x32x16_bf16(a, b, c, 0, 0, 0);
}

// =====================================================================
// fp32 -> fp16 conversion for x, Wq, Wk, Wv, Wo.
// =====================================================================
__global__ __launch_bounds__(256) void convert_kernel(
    const float* __restrict__ x,  const float* __restrict__ wq,
    const float* __restrict__ wk, const float* __restrict__ wv,
    const float* __restrict__ wo,
    f16* __restrict__ xf, f16* __restrict__ wqf, f16* __restrict__ wkf,
    f16* __restrict__ wvf, f16* __restrict__ wof)
{
  int b = blockIdx.x;
  const float* src; f16* dst; long off;
  if      (b < 2048) { src = x;  dst = xf;  off = (long)b * 1024; }
  else if (b < 3072) { src = wq; dst = wqf; off = (long)(b - 2048) * 1024; }
  else if (b < 4096) { src = wk; dst = wkf; off = (long)(b - 3072) * 1024; }
  else if (b < 5120) { src = wv; dst = wvf; off = (long)(b - 4096) * 1024; }
  else               { src = wo; dst = wof; off = (long)(b - 5120) * 1024; }
  long i = off + threadIdx.x * 4;
  float4 v = *(const float4*)(src + i);
  f16x4 o;
  o.x = (f16)v.x; o.y = (f16)v.y; o.z = (f16)v.z; o.w = (f16)v.w;
  *(f16x4*)(dst + i) = o;
}

// =====================================================================
// fp16 NT GEMM, 64x128 tile, BK=128 (two 64-wide sub-buffers with the
// proven 64-swizzle layout), 48KB LDS -> 3 blocks/CU, half the barriers.
// MODE 2 = RoPE-Q epilogue (fold 0.125) -> fp16; MODE 3 = RoPE-K (inv scale)
// MODE 0 = bf16 out (V);  MODE 1 = fp32 out (output projection)
// =====================================================================
template <int MODE>
__device__ __forceinline__ void gemm64x128_f16(
    const f16* __restrict__ A_, const f16* __restrict__ B_,
    void* C0v, int K, int ldc, int m0, int n0, char* smem)
{
  // As0 @0 (8K) | As1 @8192 (8K) | Bs0 @16384 (16K) | Bs1 @32768 (16K)
  const int tid  = threadIdx.x;
  const int wave = tid >> 6, lane = tid & 63, quad = lane >> 4, l16 = lane & 15;
  const int mo = (wave & 1) << 5;
  const int no = (wave >> 1) << 6;

  floatx4 acc[2][4];
  #pragma unroll
  for (int i = 0; i < 2; i++)
    #pragma unroll
    for (int j = 0; j < 4; j++) { acc[i][j][0]=0.f; acc[i][j][1]=0.f; acc[i][j][2]=0.f; acc[i][j][3]=0.f; }

  const int srow = tid >> 3;
  const int ch   = (tid & 7) ^ (srow & 7);
  const long aoff = (long)(m0 + srow) * K + ch * 8;
  const long boff = (long)(n0 + srow) * K + ch * 8;
  const int wb = wave << 10;

  for (int k0 = 0; k0 < K; k0 += 128) {
    #pragma unroll
    for (int s = 0; s < 2; s++) {
      #pragma unroll
      for (int rr = 0; rr < 2; rr++)
        gl_lds16(A_ + aoff + k0 + s * 64 + (long)rr * 32 * K,
                 smem + s * 8192 + wb + rr * 4096);
      #pragma unroll
      for (int rr = 0; rr < 4; rr++)
        gl_lds16(B_ + boff + k0 + s * 64 + (long)rr * 32 * K,
                 smem + 16384 + s * 16384 + wb + rr * 4096);
    }
    __syncthreads();
    #pragma unroll
    for (int kt = 0; kt < 4; kt++) {
      const f16* As = (const f16*)(smem + (kt >> 1) * 8192);
      const f16* Bs = (const f16*)(smem + 16384 + (kt >> 1) * 16384);
      const int kti = kt & 1;
      f16x8 a[2], b[4];
      #pragma unroll
      for (int i = 0; i < 2; i++) {
        int m = mo + i * 16 + l16;
        a[i] = *(const f16x8*)(As + m * 64 + ((((kti << 2) | quad) ^ (m & 7)) << 3));
      }
      #pragma unroll
      for (int j = 0; j < 4; j++) {
        int n = no + j * 16 + l16;
        b[j] = *(const f16x8*)(Bs + n * 64 + ((((kti << 2) | quad) ^ (n & 7)) << 3));
      }
      #pragma unroll
      for (int i = 0; i < 2; i++)
        #pragma unroll
        for (int j = 0; j < 4; j++)
          acc[i][j] = mfma_h(a[i], b[j], acc[i][j]);
    }
    __syncthreads();
  }

  if (MODE == 1) {
    #pragma unroll
    for (int i = 0; i < 2; i++)
      #pragma unroll
      for (int j = 0; j < 4; j++)
        #pragma unroll
        for (int r = 0; r < 4; r++) {
          int row = m0 + mo + i * 16 + quad * 4 + r;
          int col = n0 + no + j * 16 + l16;
          ((float*)C0v)[(long)row * ldc + col] = acc[i][j][r];
        }
  } else {
    unsigned short* E = (unsigned short*)smem;   // 64x128 2-byte = 16 KB
    #pragma unroll
    for (int i = 0; i < 2; i++)
      #pragma unroll
      for (int j = 0; j < 4; j++)
        #pragma unroll
        for (int r = 0; r < 4; r++) {
          int row = mo + i * 16 + quad * 4 + r;
          int col = no + j * 16 + l16;
          float v = acc[i][j][r];
          unsigned short bits;
          if (MODE == 0) {
            bf16 t = f2bf(v);
            __builtin_memcpy(&bits, &t, 2);
          } else {
            float p = __shfl_xor(v, 1, 64);
            int d = col & 63;
            float fr = (float)(m0 + row) * __expf((float)(d >> 1) * -0.28782313662425574f);
            float sn, cs;
            sincosf(fr, &sn, &cs);
            float rot = (col & 1) ? fmaf(v, cs, p * sn) : fmaf(v, cs, -p * sn);
            float power = (float)(m0 + row - 1024) * (1.0f / 512.0f);
            if (MODE == 3) power = -power;
            float sv = fmaf(2.0f, (float)(d & 31), 25.6f) * (1.0f / 89.6f);
            float s = __expf(power * __logf(sv));
            float ov = rot * s;
            if (MODE == 2) ov *= 0.125f;
            f16 t = (f16)ov;
            __builtin_memcpy(&bits, &t, 2);
          }
          E[row * 128 + col] = bits;
        }
    __syncthreads();
    const int rr0 = tid >> 4;
    const int c8  = (tid & 15) * 8;
    #pragma unroll
    for (int p2 = 0; p2 < 4; p2++) {
      int row = p2 * 16 + rr0;
      *(uint4*)((unsigned short*)C0v + (long)(m0 + row) * ldc + n0 + c8) =
          *(const uint4*)(E + row * 128 + c8);
    }
  }
}

__global__ __launch_bounds__(256) void qkv_gemm(
    const f16* __restrict__ xf,
    const f16* __restrict__ wqf, const f16* __restrict__ wkf,
    const f16* __restrict__ wvf,
    f16* __restrict__ qf, f16* __restrict__ kf, bf16* __restrict__ vt)
{
  __shared__ char smem[49152];
  int bid = blockIdx.x;
  if (bid < 256) {
    gemm64x128_f16<2>(xf, wqf, qf, 1024, 1024, (bid >> 3) * 64, (bid & 7) * 128, smem);
  } else if (bid < 512) {
    bid -= 256;
    gemm64x128_f16<3>(xf, wkf, kf, 1024, 1024, (bid >> 3) * 64, (bid & 7) * 128, smem);
  } else {
    bid -= 512;
    gemm64x128_f16<0>(wvf, xf, vt, 1024, 2048, (bid >> 4) * 64, (bid & 15) * 128, smem);
  }
}

__global__ __launch_bounds__(256) void out_gemm(const f16* __restrict__ attn,
                                                const f16* __restrict__ Wo,
                                                float* __restrict__ out)
{
  __shared__ char smem[49152];
  gemm64x128_f16<1>(attn, Wo, out, 1024, 1024,
                    (blockIdx.x >> 3) * 64, (blockIdx.x & 7) * 128, smem);
}

// =====================================================================
// Differential flash attention, 32x32x16 MFMA, 128 keys per barrier pair.
// Two copies (a/b) of the proven 64-key K/V buffers; one __syncthreads
// covers both sub-tiles -> 16 barrier pairs instead of 32. Accumulator
// count unchanged (R10 lesson). XCD swizzle retained (h = blockIdx & 7).
// LDS: Ka 2x8K | Kb 2x8K | Va 16K | Vb 16K | P 8K = 72KB.
// =====================================================================
__global__ __launch_bounds__(256) void diff_attn(
    const f16* __restrict__ qf_, const f16* __restrict__ kf_,
    const bf16* __restrict__ vt,
    const float* __restrict__ lq1, const float* __restrict__ lk1,
    const float* __restrict__ lq2, const float* __restrict__ lk2,
    f16* __restrict__ attn)
{
  __shared__ char smem[73728];

  const int tid  = threadIdx.x;
  const int wave = tid >> 6, lane = tid & 63;
  const int l32 = lane & 31, lh = lane >> 5;
  const int h  = blockIdx.x & 7;         // head pair — XCD-affine
  const int qb = blockIdx.x >> 3;        // q block 0..63 (32 rows each)
  const int hl = wave >> 1;              // head in pair
  const int ws = wave & 1;               // key-half of this wave
  const int hh = h * 2 + hl;
  const int t0 = qb * 32;

  float a1 = lq1[lane] * lk1[lane];
  float a2 = lq2[lane] * lk2[lane];
  #pragma unroll
  for (int off = 1; off < 64; off <<= 1) {
    a1 += __shfl_xor(a1, off, 64);
    a2 += __shfl_xor(a2, off, 64);
  }
  const float lam = __expf(a1) - __expf(a2) + LAMBDA_INIT;

  // Q A-frags (32 rows x 64 d): k = kt*16 + lh*8 + j
  f16x8 qfr[4];
  {
    const f16* qrow = qf_ + (long)(t0 + l32) * EMB + hh * 64 + lh * 8;
    #pragma unroll
    for (int kt = 0; kt < 4; kt++) qfr[kt] = *(const f16x8*)(qrow + kt * 16);
  }

  floatx16 o[4];
  #pragma unroll
  for (int nt = 0; nt < 4; nt++)
    #pragma unroll
    for (int r = 0; r < 16; r++) o[nt][r] = 0.f;
  float lr[16];
  #pragma unroll
  for (int r = 0; r < 16; r++) lr[r] = 0.f;

  const int srow = lane >> 3;
  const int ch   = (lane & 7) ^ srow;
  const f16*  kgp = kf_ + (long)(h * 2 + (wave & 1)) * 64 + (long)srow * EMB + ch * 8;
  const bf16* vgp = vt + (long)(h * 128 + (wave - 2) * 64 + srow) * T_SEQ + ch * 8;
  char* ldstKa = smem + wave * 8192;            // waves 0,1
  char* ldstKb = smem + 16384 + wave * 8192;
  char* ldstVa = smem + 32768 + (wave - 2) * 8192;  // waves 2,3
  char* ldstVb = smem + 49152 + (wave - 2) * 8192;

  bf16* Pw = (bf16*)(smem + 65536) + wave * 1024;   // 32x32 bf16 per wave

  for (int kb = 0; kb < T_SEQ; kb += 128) {
    if (wave < 2) {
      #pragma unroll
      for (int j = 0; j < 8; j++) {
        gl_lds16(kgp + (long)kb * EMB + (long)j * 8 * EMB, ldstKa + j * 1024);
        gl_lds16(kgp + (long)(kb + 64) * EMB + (long)j * 8 * EMB, ldstKb + j * 1024);
      }
    } else {
      #pragma unroll
      for (int j = 0; j < 8; j++) {
        gl_lds16(vgp + kb + (long)j * 8 * T_SEQ, ldstVa + j * 1024);
        gl_lds16(vgp + kb + 64 + (long)j * 8 * T_SEQ, ldstVb + j * 1024);
      }
    }
    __syncthreads();

    #pragma unroll
    for (int sub = 0; sub < 2; sub++) {
      const f16*  Ks = (const f16*)(smem + sub * 16384 + hl * 8192);
      const bf16* Vs = (const bf16*)(smem + 32768 + sub * 16384);
      // QK: S[32][ws*32..+32]
      floatx16 s;
      #pragma unroll
      for (int r = 0; r < 16; r++) s[r] = 0.f;
      #pragma unroll
      for (int kt = 0; kt < 4; kt++) {
        int krow = ws * 32 + l32;
        int c = kt * 2 + lh;
        f16x8 kfr = *(const f16x8*)(Ks + krow * 64 + ((c ^ (krow & 7)) << 3));
        s = mfma32_h(qfr[kt], kfr, s);
      }
      // static-offset softmax
      #pragma unroll
      for (int r = 0; r < 16; r++) {
        float pv = __builtin_amdgcn_exp2f(
            fmaf(s[r], 1.4426950408889634f, -17.312340490667562f));
        s[r] = pv;
        lr[r] += pv;
      }
      // P (C-layout) -> wave-private LDS (swizzled)
      #pragma unroll
      for (int r = 0; r < 16; r++) {
        int m = (r & 3) + 8 * (r >> 2) + 4 * lh;
        Pw[m * 32 + (((l32 >> 3) ^ ((m >> 1) & 3)) << 3) + (l32 & 7)] = f2bf(s[r]);
      }
      __asm__ volatile("s_waitcnt lgkmcnt(0)" ::: "memory");
      bf16x8 pf[2];
      #pragma unroll
      for (int kt = 0; kt < 2; kt++) {
        int c = kt * 2 + lh;
        pf[kt] = *(const bf16x8*)(Pw + l32 * 32 + ((c ^ ((l32 >> 1) & 3)) << 3));
      }
      // PV over own 32 keys
      #pragma unroll
      for (int nt = 0; nt < 4; nt++) {
        #pragma unroll
        for (int kt = 0; kt < 2; kt++) {
          int vrow = nt * 32 + l32;
          int c = ws * 4 + kt * 2 + lh;
          bf16x8 vf = *(const bf16x8*)(Vs + vrow * 64 + ((c ^ (vrow & 7)) << 3));
          o[nt] = mfma32_bf(pf[kt], vf, o[nt]);
        }
      }
    }
    __syncthreads();
  }

  // reduce lr across the 32 lanes of each half
  #pragma unroll
  for (int r = 0; r < 16; r++) {
    lr[r] += __shfl_xor(lr[r], 1, 64);
    lr[r] += __shfl_xor(lr[r], 2, 64);
    lr[r] += __shfl_xor(lr[r], 4, 64);
    lr[r] += __shfl_xor(lr[r], 8, 64);
    lr[r] += __shfl_xor(lr[r], 16, 64);
  }

  float* Cb = (float*)smem;                  // 2 heads x 32x128 fp32 = 32KB
  float* Lb = (float*)(smem + 32768);        // per-row denominators

  // phase 1: key-half ws==1 publishes raw O and lr
  if (ws == 1) {
    #pragma unroll
    for (int r = 0; r < 16; r++) {
      int m = (r & 3) + 8 * (r >> 2) + 4 * lh;
      #pragma unroll
      for (int nt = 0; nt < 4; nt++)
        Cb[hl * 4096 + m * 128 + nt * 32 + l32] = o[nt][r];
      if (l32 == 0) Lb[hl * 32 + m] = lr[r];
    }
  }
  __syncthreads();
  // phase 2: ws==0 merges halves and normalizes
  if (ws == 0) {
    #pragma unroll
    for (int r = 0; r < 16; r++) {
      int m = (r & 3) + 8 * (r >> 2) + 4 * lh;
      float inv = 1.0f / (lr[r] + Lb[hl * 32 + m]);
      #pragma unroll
      for (int nt = 0; nt < 4; nt++)
        o[nt][r] = (o[nt][r] + Cb[hl * 4096 + m * 128 + nt * 32 + l32]) * inv;
    }
  }
  __syncthreads();
  // phase 3: head1 publishes normalized O1
  if (hl == 1 && ws == 0) {
    #pragma unroll
    for (int r = 0; r < 16; r++) {
      int m = (r & 3) + 8 * (r >> 2) + 4 * lh;
      #pragma unroll
      for (int nt = 0; nt < 4; nt++)
        Cb[4096 + m * 128 + nt * 32 + l32] = o[nt][r];
    }
  }
  __syncthreads();
  // phase 4: head0 does diff + rms-norm + store
  if (hl == 0 && ws == 0) {
    float ss[16];
    #pragma unroll
    for (int r = 0; r < 16; r++) {
      int m = (r & 3) + 8 * (r >> 2) + 4 * lh;
      ss[r] = 0.f;
      #pragma unroll
      for (int nt = 0; nt < 4; nt++) {
        float v = o[nt][r] - lam * Cb[4096 + m * 128 + nt * 32 + l32];
        o[nt][r] = v;
        ss[r] += v * v;
      }
    }
    #pragma unroll
    for (int r = 0; r < 16; r++) {
      ss[r] += __shfl_xor(ss[r], 1, 64);
      ss[r] += __shfl_xor(ss[r], 2, 64);
      ss[r] += __shfl_xor(ss[r], 4, 64);
      ss[r] += __shfl_xor(ss[r], 8, 64);
      ss[r] += __shfl_xor(ss[r], 16, 64);
      float rms = rsqrtf(ss[r] * (1.0f / 128.0f) + 1e-5f) * (1.0f - LAMBDA_INIT);
      int m = (r & 3) + 8 * (r >> 2) + 4 * lh;
      #pragma unroll
      for (int nt = 0; nt < 4; nt++)
        attn[(long)(t0 + m) * EMB + h * 128 + nt * 32 + l32] = (f16)(o[nt][r] * rms);
    }
  }
}

// =====================================================================
extern "C" void kernel_launch(void* const* d_in, const int* in_sizes, int n_in,
                              void* d_out, int out_size, void* d_ws, size_t ws_size,
                              hipStream_t stream)
{
  (void)in_sizes; (void)n_in; (void)out_size; (void)ws_size;
  const float* x   = (const float*)d_in[0];
  const float* Wq  = (const float*)d_in[1];
  const float* Wk  = (const float*)d_in[2];
  const float* Wv  = (const float*)d_in[3];
  const float* Wo  = (const float*)d_in[4];
  const float* lq1 = (const float*)d_in[5];
  const float* lk1 = (const float*)d_in[6];
  const float* lq2 = (const float*)d_in[7];
  const float* lk2 = (const float*)d_in[8];
  float* out = (float*)d_out;

  const size_t TM = (size_t)T_SEQ * EMB;  // 2M elems
  const size_t WM = (size_t)EMB * EMB;    // 1M elems
  bf16* vtws = (bf16*)d_ws;          // 4MB
  f16*  aws  = (f16*)(vtws + TM);    // 4MB
  f16*  xf   = aws  + TM;            // 4MB
  f16*  wqf  = xf   + TM;            // 2MB
  f16*  wkf  = wqf  + WM;
  f16*  wvf  = wkf  + WM;
  f16*  wof  = wvf  + WM;
  f16*  qf   = wof  + WM;            // 4MB
  f16*  kf   = qf   + TM;            // 4MB

  convert_kernel<<<6144, 256, 0, stream>>>(x, Wq, Wk, Wv, Wo,
                                           xf, wqf, wkf, wvf, wof);
  qkv_gemm<<<768, 256, 0, stream>>>(xf, wqf, wkf, wvf, qf, kf, vtws);
  diff_attn<<<512, 256, 0, stream>>>(qf, kf, vtws, lq1, lk1, lq2, lk2, aws);
  out_gemm<<<256, 256, 0, stream>>>(aws, wof, out);
}

// Round 14
// 188.950 us; speedup vs baseline: 1.0606x; 1.0606x over previous
//
#include <hip/hip_runtime.h>
#include <hip/hip_bf16.h>

typedef __hip_bfloat16 bf16;
typedef _Float16 f16;
typedef __attribute__((ext_vector_type(8))) __bf16 bf16x8;
typedef __attribute__((ext_vector_type(8))) _Float16 f16x8;
typedef __attribute__((ext_vector_type(4))) _Float16 f16x4;
typedef __attribute__((ext_vector_type(4))) float floatx4;
typedef __attribute__((ext_vector_type(16))) float floatx16;

#define T_SEQ 2048
#define EMB   1024
#define LAMBDA_INIT 0.35550906759096926f

// round-to-nearest-even fp32 -> bf16
__device__ __forceinline__ bf16 f2bf(float f) {
  unsigned u;
  __builtin_memcpy(&u, &f, 4);
  u += 0x7FFF + ((u >> 16) & 1);
  unsigned short h = (unsigned short)(u >> 16);
  bf16 r;
  __builtin_memcpy(&r, &h, 2);
  return r;
}

__device__ __forceinline__ void gl_lds16(const void* g, void* l) {
  __builtin_amdgcn_global_load_lds((const __attribute__((address_space(1))) void*)g,
                                   (__attribute__((address_space(3))) void*)l, 16, 0, 0);
}

__device__ __forceinline__ floatx4 mfma_h(f16x8 a, f16x8 b, floatx4 c) {
  return __builtin_amdgcn_mfma_f32_16x16x32_f16(a, b, c, 0, 0, 0);
}
__device__ __forceinline__ floatx16 mfma32_h(f16x8 a, f16x8 b, floatx16 c) {
  return __builtin_amdgcn_mfma_f32_32x32x16_f16(a, b, c, 0, 0, 0);
}
__device__ __forceinline__ floatx16 mfma32_bf(bf16x8 a, bf16x8 b, floatx16 c) {
  return __builtin_amdgcn_mfma_f32_32x32x16_bf16(a, b, c, 0, 0, 0);
}

// =====================================================================
// fp32 -> fp16 conversion for x, Wq, Wk, Wv, Wo.
// =====================================================================
__global__ __launch_bounds__(256) void convert_kernel(
    const float* __restrict__ x,  const float* __restrict__ wq,
    const float* __restrict__ wk, const float* __restrict__ wv,
    const float* __restrict__ wo,
    f16* __restrict__ xf, f16* __restrict__ wqf, f16* __restrict__ wkf,
    f16* __restrict__ wvf, f16* __restrict__ wof)
{
  int b = blockIdx.x;
  const float* src; f16* dst; long off;
  if      (b < 2048) { src = x;  dst = xf;  off = (long)b * 1024; }
  else if (b < 3072) { src = wq; dst = wqf; off = (long)(b - 2048) * 1024; }
  else if (b < 4096) { src = wk; dst = wkf; off = (long)(b - 3072) * 1024; }
  else if (b < 5120) { src = wv; dst = wvf; off = (long)(b - 4096) * 1024; }
  else               { src = wo; dst = wof; off = (long)(b - 5120) * 1024; }
  long i = off + threadIdx.x * 4;
  float4 v = *(const float4*)(src + i);
  f16x4 o;
  o.x = (f16)v.x; o.y = (f16)v.y; o.z = (f16)v.z; o.w = (f16)v.w;
  *(f16x4*)(dst + i) = o;
}

// =====================================================================
// fp16 NT GEMM, 64x128 tile, BK=64, 24KB LDS staging (R12-proven).
// MODE 2 = RoPE-Q epilogue -> row-major f16
// MODE 3 = RoPE-K epilogue -> K fragment-order f16:
//          idx = (((hh*32+kb)*8+c)*64 + krow)*8,  d = c*8+j
// MODE 0 = V -> fragment-order bf16:
//          idx = (((h*32+kb)*8+c)*128 + vrow)*8,  keys kb*64+c*8+j
// MODE 1 = fp32 out (output projection)
// =====================================================================
template <int MODE>
__device__ __forceinline__ void gemm64x128_f16(
    const f16* __restrict__ A_, const f16* __restrict__ B_,
    void* C0v, int K, int ldc, int m0, int n0, char* smem)
{
  f16* As = (f16*)smem;              // 64 x 64 swz (8 KB)
  f16* Bs = (f16*)(smem + 8192);     // 128 x 64 swz (16 KB)
  const int tid  = threadIdx.x;
  const int wave = tid >> 6, lane = tid & 63, quad = lane >> 4, l16 = lane & 15;
  const int mo = (wave & 1) << 5;
  const int no = (wave >> 1) << 6;

  floatx4 acc[2][4];
  #pragma unroll
  for (int i = 0; i < 2; i++)
    #pragma unroll
    for (int j = 0; j < 4; j++) { acc[i][j][0]=0.f; acc[i][j][1]=0.f; acc[i][j][2]=0.f; acc[i][j][3]=0.f; }

  const int srow = tid >> 3;
  const int ch   = (tid & 7) ^ (srow & 7);
  const long aoff = (long)(m0 + srow) * K + ch * 8;
  const long boff = (long)(n0 + srow) * K + ch * 8;
  const int wb = wave << 10;

  for (int k0 = 0; k0 < K; k0 += 64) {
    #pragma unroll
    for (int rr = 0; rr < 2; rr++)
      gl_lds16(A_ + aoff + k0 + (long)rr * 32 * K, smem + wb + rr * 4096);
    #pragma unroll
    for (int rr = 0; rr < 4; rr++)
      gl_lds16(B_ + boff + k0 + (long)rr * 32 * K, smem + 8192 + wb + rr * 4096);
    __syncthreads();
    #pragma unroll
    for (int kt = 0; kt < 2; kt++) {
      f16x8 a[2], b[4];
      #pragma unroll
      for (int i = 0; i < 2; i++) {
        int m = mo + i * 16 + l16;
        a[i] = *(const f16x8*)(As + m * 64 + ((((kt << 2) | quad) ^ (m & 7)) << 3));
      }
      #pragma unroll
      for (int j = 0; j < 4; j++) {
        int n = no + j * 16 + l16;
        b[j] = *(const f16x8*)(Bs + n * 64 + ((((kt << 2) | quad) ^ (n & 7)) << 3));
      }
      #pragma unroll
      for (int i = 0; i < 2; i++)
        #pragma unroll
        for (int j = 0; j < 4; j++)
          acc[i][j] = mfma_h(a[i], b[j], acc[i][j]);
    }
    __syncthreads();
  }

  if (MODE == 1) {
    #pragma unroll
    for (int i = 0; i < 2; i++)
      #pragma unroll
      for (int j = 0; j < 4; j++)
        #pragma unroll
        for (int r = 0; r < 4; r++) {
          int row = m0 + mo + i * 16 + quad * 4 + r;
          int col = n0 + no + j * 16 + l16;
          ((float*)C0v)[(long)row * ldc + col] = acc[i][j][r];
        }
  } else {
    unsigned short* E = (unsigned short*)smem;   // 64x128 2-byte = 16 KB
    #pragma unroll
    for (int i = 0; i < 2; i++)
      #pragma unroll
      for (int j = 0; j < 4; j++)
        #pragma unroll
        for (int r = 0; r < 4; r++) {
          int row = mo + i * 16 + quad * 4 + r;
          int col = no + j * 16 + l16;
          float v = acc[i][j][r];
          unsigned short bits;
          if (MODE == 0) {
            bf16 t = f2bf(v);
            __builtin_memcpy(&bits, &t, 2);
          } else {
            float p = __shfl_xor(v, 1, 64);
            int d = col & 63;
            float fr = (float)(m0 + row) * __expf((float)(d >> 1) * -0.28782313662425574f);
            float sn, cs;
            sincosf(fr, &sn, &cs);
            float rot = (col & 1) ? fmaf(v, cs, p * sn) : fmaf(v, cs, -p * sn);
            float power = (float)(m0 + row - 1024) * (1.0f / 512.0f);
            if (MODE == 3) power = -power;
            float sv = fmaf(2.0f, (float)(d & 31), 25.6f) * (1.0f / 89.6f);
            float s = __expf(power * __logf(sv));
            float ov = rot * s;
            if (MODE == 2) ov *= 0.125f;
            f16 t = (f16)ov;
            __builtin_memcpy(&bits, &t, 2);
          }
          E[row * 128 + col] = bits;
        }
    __syncthreads();
    const int rr0 = tid >> 4;
    const int c8  = (tid & 15) * 8;
    #pragma unroll
    for (int p2 = 0; p2 < 4; p2++) {
      int row = p2 * 16 + rr0;
      uint4 val = *(const uint4*)(E + row * 128 + c8);
      long g;
      if (MODE == 2) {
        g = (long)(m0 + row) * ldc + n0 + c8;                     // row-major Q
      } else if (MODE == 3) {
        int hhW = (n0 + c8) >> 6;                                 // head
        int cW  = (c8 & 63) >> 3;                                 // d-chunk
        g = (((long)hhW * 32 + (m0 >> 6)) * 8 + cW) * 512 + (long)row * 8;
      } else {                                                    // MODE 0: V frag
        int vg = m0 + row;
        int hW = vg >> 7, vl = vg & 127;
        int key0 = n0 + c8;
        int kbW = key0 >> 6, cW = (key0 & 63) >> 3;
        g = (((long)hW * 32 + kbW) * 8 + cW) * 1024 + (long)vl * 8;
      }
      *(uint4*)((unsigned short*)C0v + g) = val;
    }
  }
}

__global__ __launch_bounds__(256) void qkv_gemm(
    const f16* __restrict__ xf,
    const f16* __restrict__ wqf, const f16* __restrict__ wkf,
    const f16* __restrict__ wvf,
    f16* __restrict__ qf, f16* __restrict__ kf, bf16* __restrict__ vt)
{
  __shared__ char smem[24576];
  int bid = blockIdx.x;
  if (bid < 256) {
    gemm64x128_f16<2>(xf, wqf, qf, 1024, 1024, (bid >> 3) * 64, (bid & 7) * 128, smem);
  } else if (bid < 512) {
    bid -= 256;
    gemm64x128_f16<3>(xf, wkf, kf, 1024, 1024, (bid >> 3) * 64, (bid & 7) * 128, smem);
  } else {
    bid -= 512;
    gemm64x128_f16<0>(wvf, xf, vt, 1024, 2048, (bid >> 4) * 64, (bid & 15) * 128, smem);
  }
}

__global__ __launch_bounds__(256) void out_gemm(const f16* __restrict__ attn,
                                                const f16* __restrict__ Wo,
                                                float* __restrict__ out)
{
  __shared__ char smem[24576];
  gemm64x128_f16<1>(attn, Wo, out, 1024, 1024,
                    (blockIdx.x >> 3) * 64, (blockIdx.x & 7) * 128, smem);
}

// =====================================================================
// Differential flash attention — BARRIER-FREE K-loop.
// K/V live in global memory in MFMA-fragment order (written by qkv_gemm),
// so each wave streams its fragments straight from L2 into VGPRs with
// fully-coalesced b128 loads: no LDS staging, no __syncthreads in the
// loop. Depth-1 register prefetch (unrolled x2, no copy rotation).
// Wave = (head hl, key-half ws); P transpose stays wave-private in LDS
// (lgkmcnt-only). Epilogue: 3 barriers for half-merge + diff + rmsnorm.
// XCD swizzle retained (h = blockIdx & 7) — keeps K/V L2-resident.
// =====================================================================
__global__ __launch_bounds__(256, 2) void diff_attn(
    const f16* __restrict__ qf_, const f16* __restrict__ kfr,
    const bf16* __restrict__ vfr,
    const float* __restrict__ lq1, const float* __restrict__ lk1,
    const float* __restrict__ lq2, const float* __restrict__ lk2,
    f16* __restrict__ attn)
{
  __shared__ char smem[41216];
  // Pw @0 (4 waves x 2KB = 8KB) | Cb @8192 (32KB) | Lb @40960 (64 f32)
  float* Cb = (float*)(smem + 8192);
  float* Lb = (float*)(smem + 40960);

  const int tid  = threadIdx.x;
  const int wave = tid >> 6, lane = tid & 63;
  const int l32 = lane & 31, lh = lane >> 5;
  const int h  = blockIdx.x & 7;         // head pair — XCD-affine
  const int qb = blockIdx.x >> 3;        // q block 0..63 (32 rows each)
  const int hl = wave >> 1;              // head in pair
  const int ws = wave & 1;               // key-half of this wave
  const int hh = h * 2 + hl;
  const int t0 = qb * 32;

  float a1 = lq1[lane] * lk1[lane];
  float a2 = lq2[lane] * lk2[lane];
  #pragma unroll
  for (int off = 1; off < 64; off <<= 1) {
    a1 += __shfl_xor(a1, off, 64);
    a2 += __shfl_xor(a2, off, 64);
  }
  const float lam = __expf(a1) - __expf(a2) + LAMBDA_INIT;

  // Q A-frags (32 rows x 64 d): k = kt*16 + lh*8 + j
  f16x8 qfr[4];
  {
    const f16* qrow = qf_ + (long)(t0 + l32) * EMB + hh * 64 + lh * 8;
    #pragma unroll
    for (int kt = 0; kt < 4; kt++) qfr[kt] = *(const f16x8*)(qrow + kt * 16);
  }

  floatx16 o[4];
  #pragma unroll
  for (int nt = 0; nt < 4; nt++)
    #pragma unroll
    for (int r = 0; r < 16; r++) o[nt][r] = 0.f;
  float lr[16];
  #pragma unroll
  for (int r = 0; r < 16; r++) lr[r] = 0.f;

  // fragment bases: K idx = (((hh*32+kb)*8+c)*64 + ws*32+l32)*8, c = kt*2+lh
  //                 V idx = (((h*32+kb)*8+c)*128 + nt*32+l32)*8, c = ws*4+kt*2+lh
  const f16*  kbase = kfr + (long)hh * 131072 + (ws * 32 + l32) * 8;
  const bf16* vbase = vfr + (long)h * 262144 + l32 * 8;

  auto loadK = [&](int kb, f16x8* d) {
    const f16* p = kbase + (long)kb * 4096;
    #pragma unroll
    for (int kt = 0; kt < 4; kt++) d[kt] = *(const f16x8*)(p + (kt * 2 + lh) * 512);
  };
  auto loadV = [&](int kb, bf16x8* d) {
    const bf16* p = vbase + (long)kb * 8192;
    #pragma unroll
    for (int kt = 0; kt < 2; kt++)
      #pragma unroll
      for (int nt = 0; nt < 4; nt++)
        d[kt * 4 + nt] = *(const bf16x8*)(p + (ws * 4 + kt * 2 + lh) * 1024 + nt * 256);
  };

  bf16* Pw = (bf16*)smem + wave * 1024;   // 32x32 bf16, wave-private

  auto compute = [&](const f16x8* kc, const bf16x8* vc) {
    floatx16 s;
    #pragma unroll
    for (int r = 0; r < 16; r++) s[r] = 0.f;
    #pragma unroll
    for (int kt = 0; kt < 4; kt++) s = mfma32_h(qfr[kt], kc[kt], s);
    #pragma unroll
    for (int r = 0; r < 16; r++) {
      float pv = __builtin_amdgcn_exp2f(
          fmaf(s[r], 1.4426950408889634f, -17.312340490667562f));
      s[r] = pv;
      lr[r] += pv;
    }
    #pragma unroll
    for (int r = 0; r < 16; r++) {
      int m = (r & 3) + 8 * (r >> 2) + 4 * lh;
      Pw[m * 32 + (((l32 >> 3) ^ ((m >> 1) & 3)) << 3) + (l32 & 7)] = f2bf(s[r]);
    }
    __asm__ volatile("s_waitcnt lgkmcnt(0)" ::: "memory");
    bf16x8 pf[2];
    #pragma unroll
    for (int kt = 0; kt < 2; kt++) {
      int c = kt * 2 + lh;
      pf[kt] = *(const bf16x8*)(Pw + l32 * 32 + ((c ^ ((l32 >> 1) & 3)) << 3));
    }
    #pragma unroll
    for (int nt = 0; nt < 4; nt++)
      #pragma unroll
      for (int kt = 0; kt < 2; kt++)
        o[nt] = mfma32_bf(pf[kt], vc[kt * 4 + nt], o[nt]);
  };

  f16x8 k0[4], k1[4];
  bf16x8 v0[8], v1[8];
  loadK(0, k0); loadV(0, v0);
  for (int kb = 0; kb < 32; kb += 2) {
    loadK(kb + 1, k1); loadV(kb + 1, v1);
    compute(k0, v0);
    if (kb + 2 < 32) { loadK(kb + 2, k0); loadV(kb + 2, v0); }
    compute(k1, v1);
  }

  // reduce lr across the 32 columns (same lh half)
  #pragma unroll
  for (int r = 0; r < 16; r++) {
    lr[r] += __shfl_xor(lr[r], 1, 64);
    lr[r] += __shfl_xor(lr[r], 2, 64);
    lr[r] += __shfl_xor(lr[r], 4, 64);
    lr[r] += __shfl_xor(lr[r], 8, 64);
    lr[r] += __shfl_xor(lr[r], 16, 64);
  }

  // phase 1: key-half ws==1 publishes raw O and lr (Cb doesn't overlap Pw)
  if (ws == 1) {
    #pragma unroll
    for (int r = 0; r < 16; r++) {
      int m = (r & 3) + 8 * (r >> 2) + 4 * lh;
      #pragma unroll
      for (int nt = 0; nt < 4; nt++)
        Cb[hl * 4096 + m * 128 + nt * 32 + l32] = o[nt][r];
      if (l32 == 0) Lb[hl * 32 + m] = lr[r];
    }
  }
  __syncthreads();
  // phase 2: ws==0 merges halves and normalizes
  if (ws == 0) {
    #pragma unroll
    for (int r = 0; r < 16; r++) {
      int m = (r & 3) + 8 * (r >> 2) + 4 * lh;
      float inv = 1.0f / (lr[r] + Lb[hl * 32 + m]);
      #pragma unroll
      for (int nt = 0; nt < 4; nt++)
        o[nt][r] = (o[nt][r] + Cb[hl * 4096 + m * 128 + nt * 32 + l32]) * inv;
    }
  }
  __syncthreads();
  // phase 3: head1 publishes normalized O1
  if (hl == 1 && ws == 0) {
    #pragma unroll
    for (int r = 0; r < 16; r++) {
      int m = (r & 3) + 8 * (r >> 2) + 4 * lh;
      #pragma unroll
      for (int nt = 0; nt < 4; nt++)
        Cb[4096 + m * 128 + nt * 32 + l32] = o[nt][r];
    }
  }
  __syncthreads();
  // phase 4: head0 does diff + rms-norm + store
  if (hl == 0 && ws == 0) {
    float ss[16];
    #pragma unroll
    for (int r = 0; r < 16; r++) {
      int m = (r & 3) + 8 * (r >> 2) + 4 * lh;
      ss[r] = 0.f;
      #pragma unroll
      for (int nt = 0; nt < 4; nt++) {
        float v = o[nt][r] - lam * Cb[4096 + m * 128 + nt * 32 + l32];
        o[nt][r] = v;
        ss[r] += v * v;
      }
    }
    #pragma unroll
    for (int r = 0; r < 16; r++) {
      ss[r] += __shfl_xor(ss[r], 1, 64);
      ss[r] += __shfl_xor(ss[r], 2, 64);
      ss[r] += __shfl_xor(ss[r], 4, 64);
      ss[r] += __shfl_xor(ss[r], 8, 64);
      ss[r] += __shfl_xor(ss[r], 16, 64);
      float rms = rsqrtf(ss[r] * (1.0f / 128.0f) + 1e-5f) * (1.0f - LAMBDA_INIT);
      int m = (r & 3) + 8 * (r >> 2) + 4 * lh;
      #pragma unroll
      for (int nt = 0; nt < 4; nt++)
        attn[(long)(t0 + m) * EMB + h * 128 + nt * 32 + l32] = (f16)(o[nt][r] * rms);
    }
  }
}

// =====================================================================
extern "C" void kernel_launch(void* const* d_in, const int* in_sizes, int n_in,
                              void* d_out, int out_size, void* d_ws, size_t ws_size,
                              hipStream_t stream)
{
  (void)in_sizes; (void)n_in; (void)out_size; (void)ws_size;
  const float* x   = (const float*)d_in[0];
  const float* Wq  = (const float*)d_in[1];
  const float* Wk  = (const float*)d_in[2];
  const float* Wv  = (const float*)d_in[3];
  const float* Wo  = (const float*)d_in[4];
  const float* lq1 = (const float*)d_in[5];
  const float* lk1 = (const float*)d_in[6];
  const float* lq2 = (const float*)d_in[7];
  const float* lk2 = (const float*)d_in[8];
  float* out = (float*)d_out;

  const size_t TM = (size_t)T_SEQ * EMB;  // 2M elems
  const size_t WM = (size_t)EMB * EMB;    // 1M elems
  bf16* vtws = (bf16*)d_ws;          // 4MB (V fragment-order)
  f16*  aws  = (f16*)(vtws + TM);    // 4MB
  f16*  xf   = aws  + TM;            // 4MB
  f16*  wqf  = xf   + TM;            // 2MB
  f16*  wkf  = wqf  + WM;
  f16*  wvf  = wkf  + WM;
  f16*  wof  = wvf  + WM;
  f16*  qf   = wof  + WM;            // 4MB (row-major)
  f16*  kf   = qf   + TM;            // 4MB (K fragment-order)

  convert_kernel<<<6144, 256, 0, stream>>>(x, Wq, Wk, Wv, Wo,
                                           xf, wqf, wkf, wvf, wof);
  qkv_gemm<<<768, 256, 0, stream>>>(xf, wqf, wkf, wvf, qf, kf, vtws);
  diff_attn<<<512, 256, 0, stream>>>(qf, kf, vtws, lq1, lk1, lq2, lk2, aws);
  out_gemm<<<256, 256, 0, stream>>>(aws, wof, out);
}